// Round 18
// baseline (135544.238 us; speedup 1.0000x reference)
//
#include <hip/hip_runtime.h>
#include <math.h>

#define N_PTS 16384
#define KNN 20
#define NRANGE 4
#define C_RANGE (N_PTS / NRANGE)       // 4096
#define TILES_PER_RANGE (C_RANGE / 64) // 64
#define QCAP 64

// ---------------- pack x + squared norm ----------------
__global__ void pack3_kernel(const float* __restrict__ x, float4* __restrict__ xp) {
  int i = blockIdx.x * blockDim.x + threadIdx.x;
  {
    #pragma clang fp contract(off)
    float a = x[i*3+0], b = x[i*3+1], c = x[i*3+2];
    xp[i] = make_float4(a, b, c, a*a + b*b + c*c);
  }
}

__global__ void sq64_kernel(const float* __restrict__ h, float* __restrict__ sq) {
  int i = blockIdx.x * blockDim.x + threadIdx.x;
  const float4* r = (const float4*)(h + (long)i*64);
  {
    #pragma clang fp contract(off)
    float ax=0.f, ay=0.f, az=0.f, aw=0.f;
    for (int t=0; t<16; t++) {
      float4 v = r[t];
      ax += v.x*v.x; ay += v.y*v.y; az += v.z*v.z; aw += v.w*v.w;
    }
    sq[i] = (ax+ay)+(az+aw);
  }
}

// ---------------- transpose h1 [pt][64] -> hTt [tile][dim][cand64] ----------------
// Block b covers points b*64..b*64+63 == global candidate tile b; its output is
// a contiguous 16 KB chunk, so knn64's d-loop can use immediate load offsets.
__global__ __launch_bounds__(256) void transpose64_kernel(const float* __restrict__ h,
                                                          float* __restrict__ hTt) {
  __shared__ float t[64][65];
  int b = blockIdx.x;
  int tid = threadIdx.x;
  int r = tid >> 2, c4 = (tid & 3) * 16;
  #pragma unroll
  for (int k = 0; k < 4; k++) {
    float4 v = *(const float4*)(h + (size_t)(b*64+r)*64 + c4 + k*4);
    t[c4+k*4+0][r] = v.x; t[c4+k*4+1][r] = v.y; t[c4+k*4+2][r] = v.z; t[c4+k*4+3][r] = v.w;
  }
  __syncthreads();
  int d = tid >> 2, p4 = (tid & 3) * 16;
  #pragma unroll
  for (int k = 0; k < 4; k++) {
    float4 o;
    o.x = t[d][p4+k*4+0]; o.y = t[d][p4+k*4+1]; o.z = t[d][p4+k*4+2]; o.w = t[d][p4+k*4+3];
    *(float4*)(hTt + ((size_t)b*64 + d)*64 + p4 + k*4) = o;
  }
}

// register top-20: replace current lex-max with (e,ei), rescan for new max.
__device__ __forceinline__ void t20_replace_rescan(float (&rd)[KNN], int (&ri)[KNN],
                                                   float &maxd, int &maxi, int &maxp,
                                                   float e, int ei) {
  #pragma unroll
  for (int k = 0; k < KNN; k++) if (k == maxp) { rd[k] = e; ri[k] = ei; }
  float md = rd[0]; int mi = ri[0]; int mp = 0;
  #pragma unroll
  for (int k = 1; k < KNN; k++) {
    bool g = (rd[k] > md) || (rd[k] == md && ri[k] > mi);
    md = g ? rd[k] : md; mi = g ? ri[k] : mi; mp = g ? k : mp;
  }
  maxd = md; maxi = mi; maxp = mp;
}

// wave-internal fence: drain outstanding LDS ops + stop compiler reordering
#define WAVE_LDS_FENCE() asm volatile("s_waitcnt lgkmcnt(0)" ::: "memory")

// drain: lanes 0..15 fold their query's queued survivors into register lists.
// Queue index is a uchar local offset within the tile; rebased with CT0 here.
#define WDRAIN(CT0)                                                    \
  do {                                                                 \
    WAVE_LDS_FENCE();                                                  \
    if (l < 16) {                                                      \
      int n = cnt[wv][l]; if (n > QCAP) n = QCAP;                      \
      for (int s = 0; s < n; s++) {                                    \
        float e = qd[wv][l][s]; int ei = (CT0) + (int)qidx[wv][l][s];  \
        if (e < maxd || (e == maxd && ei < maxi))                      \
          t20_replace_rescan(rd, ri, maxd, maxi, maxp, e, ei);         \
      }                                                                \
      cnt[wv][l] = 0;                                                  \
      w19[wv][l] = maxd;                                               \
    }                                                                  \
    WAVE_LDS_FENCE();                                                  \
  } while (0)

// sorted emit: 20 lex-min extractions from the register list
#define EMIT(PD, PI, QBASE)                                            \
  do {                                                                 \
    if (l < 16) {                                                      \
      size_t o = ((size_t)((QBASE) + l)*NRANGE + rg)*KNN;              \
      for (int k = 0; k < KNN; k++) {                                  \
        float md = rd[0]; int mi = ri[0]; int mp = 0;                  \
        _Pragma("unroll")                                              \
        for (int t = 1; t < KNN; t++) {                                \
          bool g = (rd[t] < md) || (rd[t] == md && ri[t] < mi);        \
          md = g ? rd[t] : md; mi = g ? ri[t] : mi; mp = g ? t : mp;   \
        }                                                              \
        PD[o+k] = md; PI[o+k] = mi;                                    \
        _Pragma("unroll")                                              \
        for (int t = 0; t < KNN; t++) if (t == mp) rd[t] = INFINITY;   \
      }                                                                \
    }                                                                  \
  } while (0)

// ---------------- knn D=64: wave-owned queries, register lists ----------------
// Full-tile push window (64 cands) + ONE drain per tile; candidate loads use
// tile-contiguous layout -> 16 immediate-offset loads per base-pointer update.
__global__ __launch_bounds__(256, 4) void knn64_wq(const float* __restrict__ h,
                                                   const float* __restrict__ hTt,
                                                   const float* __restrict__ sq,
                                                   float* __restrict__ pd,
                                                   int* __restrict__ pi) {
  __shared__ float qT[4][64][16];     // [wave][dim][16 queries], 64B rows
  __shared__ float qd[4][16][QCAP];
  __shared__ unsigned char qidx[4][16][QCAP];
  __shared__ float w19[4][16];
  __shared__ int   cnt[4][16];

  int tid = threadIdx.x;
  int wv = tid >> 6;
  int l  = tid & 63;
  int qb = blockIdx.x >> 2, rg = blockIdx.x & 3;
  int q0 = qb*64, c0 = rg*C_RANGE;
  int qw0 = q0 + wv*16;

  float rd[KNN]; int ri[KNN];
  #pragma unroll
  for (int k = 0; k < KNN; k++) { rd[k] = INFINITY; ri[k] = 0x7fffffff; }
  float maxd = INFINITY; int maxi = 0x7fffffff; int maxp = 0;

  if (l < 16) { w19[wv][l] = INFINITY; cnt[wv][l] = 0; }
  {
    int lq = l & 15, m = l >> 4;
    #pragma unroll
    for (int k = 0; k < 4; k++) {
      float4 v = *(const float4*)(h + (size_t)(qw0+lq)*64 + m*16 + k*4);
      qT[wv][m*16+k*4+0][lq] = v.x; qT[wv][m*16+k*4+1][lq] = v.y;
      qT[wv][m*16+k*4+2][lq] = v.z; qT[wv][m*16+k*4+3][lq] = v.w;
    }
  }
  WAVE_LDS_FENCE();

  int qrow0 = (l >> 4) * 4;
  int crow0 = (l & 15) * 4;
  float qsv[4];
  #pragma unroll
  for (int i=0;i<4;i++) qsv[i] = sq[qw0 + qrow0 + i];

  for (int tile = 0; tile < TILES_PER_RANGE; tile++) {
    int ct0 = c0 + tile*64;
    float acc[4][4];
    #pragma unroll
    for (int i=0;i<4;i++)
      #pragma unroll
      for (int j=0;j<4;j++) acc[i][j] = 0.f;

    // tile-contiguous candidates: 16 KB chunk, immediate offsets within 4 KB groups
    const float* tbase = hTt + ((size_t)(ct0 >> 6))*4096 + crow0;
    #pragma unroll
    for (int dg = 0; dg < 4; dg++) {
      const float* bp = tbase + dg*1024;     // 16 dims * 64 floats
      #pragma unroll
      for (int dd = 0; dd < 16; dd++) {
        int d = dg*16 + dd;
        float4 cv = *(const float4*)(bp + dd*64);   // imm offset dd*256B <= 3840
        float4 qv = *(float4*)&qT[wv][d][qrow0];    // ds_read_b128, imm offset
        acc[0][0] += qv.x*cv.x; acc[0][1] += qv.x*cv.y; acc[0][2] += qv.x*cv.z; acc[0][3] += qv.x*cv.w;
        acc[1][0] += qv.y*cv.x; acc[1][1] += qv.y*cv.y; acc[1][2] += qv.y*cv.z; acc[1][3] += qv.y*cv.w;
        acc[2][0] += qv.z*cv.x; acc[2][1] += qv.z*cv.y; acc[2][2] += qv.z*cv.z; acc[2][3] += qv.z*cv.w;
        acc[3][0] += qv.w*cv.x; acc[3][1] += qv.w*cv.y; acc[3][2] += qv.w*cv.z; acc[3][3] += qv.w*cv.w;
      }
    }

    float csv[4];
    #pragma unroll
    for (int j=0;j<4;j++) csv[j] = sq[ct0+crow0+j];

    // single full-tile push phase (all lanes active)
    #pragma unroll
    for (int i=0;i<4;i++) {
      int lq = qrow0 + i;
      float w = w19[wv][lq];
      #pragma unroll
      for (int j=0;j<4;j++) {
        float dd = (qsv[i] + csv[j]) - 2.0f*acc[i][j];
        if (dd < w) {
          int slot = atomicAdd(&cnt[wv][lq], 1);
          qd[wv][lq][slot] = dd;
          qidx[wv][lq][slot] = (unsigned char)(crow0 + j);
        }
      }
    }
    WDRAIN(ct0);
  }

  EMIT(pd, pi, qw0);
}

// ---------------- knn D=3: wave-owned queries, register lists ----------------
__global__ __launch_bounds__(256, 4) void knn3_wq(const float4* __restrict__ xp,
                                                  float* __restrict__ pd,
                                                  int* __restrict__ pi) {
  __shared__ float qd[4][16][QCAP];
  __shared__ unsigned char qidx[4][16][QCAP];
  __shared__ float w19[4][16];
  __shared__ int   cnt[4][16];

  int tid = threadIdx.x;
  int wv = tid >> 6;
  int l  = tid & 63;
  int qb = blockIdx.x >> 2, rg = blockIdx.x & 3;
  int q0 = qb*64, c0 = rg*C_RANGE;
  int qw0 = q0 + wv*16;

  float rd[KNN]; int ri[KNN];
  #pragma unroll
  for (int k = 0; k < KNN; k++) { rd[k] = INFINITY; ri[k] = 0x7fffffff; }
  float maxd = INFINITY; int maxi = 0x7fffffff; int maxp = 0;

  if (l < 16) { w19[wv][l] = INFINITY; cnt[wv][l] = 0; }
  WAVE_LDS_FENCE();

  int qrow0 = (l >> 4) * 4;
  int crow0 = (l & 15) * 4;
  float4 qv[4];
  #pragma unroll
  for (int i=0;i<4;i++) qv[i] = xp[qw0 + qrow0 + i];

  for (int tile = 0; tile < TILES_PER_RANGE; tile++) {
    int ct0 = c0 + tile*64;
    float4 cv[4];
    #pragma unroll
    for (int j=0;j<4;j++) cv[j] = xp[ct0 + crow0 + j];

    #pragma unroll
    for (int i=0;i<4;i++) {
      int lq = qrow0 + i;
      float w = w19[wv][lq];
      #pragma unroll
      for (int j=0;j<4;j++) {
        float dd = (qv[i].w + cv[j].w)
                 - 2.0f*(qv[i].x*cv[j].x + qv[i].y*cv[j].y + qv[i].z*cv[j].z);
        if (dd < w) {
          int slot = atomicAdd(&cnt[wv][lq], 1);
          qd[wv][lq][slot] = dd;
          qidx[wv][lq][slot] = (unsigned char)(crow0 + j);
        }
      }
    }
    WDRAIN(ct0);
  }

  EMIT(pd, pi, qw0);
}

// ---------------- merge NRANGE sorted partial lists -> top-20 ----------------
__global__ void knn_merge_kernel(const float* __restrict__ pd, const int* __restrict__ pi,
                                 int* __restrict__ out_idx) {
  int qi = blockIdx.x*256 + threadIdx.x;
  const float* bd = pd + (size_t)qi*NRANGE*KNN;
  const int*   bi = pi + (size_t)qi*NRANGE*KNN;
  int ptr[NRANGE];
  #pragma unroll
  for (int r=0;r<NRANGE;r++) ptr[r] = 0;
  for (int k = 0; k < KNN; k++) {
    float best = INFINITY; int besti = 0x7fffffff; int br = 0;
    #pragma unroll
    for (int r = 0; r < NRANGE; r++) {
      float d = bd[r*KNN + ptr[r]];
      int   ii = bi[r*KNN + ptr[r]];
      bool better = (ptr[r] < KNN) && (d < best || (d == best && ii < besti));
      if (better) { best = d; besti = ii; br = r; }
    }
    #pragma unroll
    for (int r=0;r<NRANGE;r++) ptr[r] += (r == br) ? 1 : 0;
    out_idx[qi*KNN + k] = besti;
  }
}

// ---------------- edge_conv1 precompute ----------------
__global__ void cg1_kernel(const float* __restrict__ x, const float* __restrict__ W1,
                           const float* __restrict__ b1,
                           float* __restrict__ C1, float* __restrict__ G1) {
  int gid = blockIdx.x*256 + threadIdx.x;   // 16384*64
  int i = gid >> 6, c = gid & 63;
  float x0 = x[i*3+0], x1 = x[i*3+1], x2 = x[i*3+2];
  float wt0 = W1[0*64+c], wt1 = W1[1*64+c], wt2 = W1[2*64+c];
  float wb0 = W1[3*64+c], wb1 = W1[4*64+c], wb2 = W1[5*64+c];
  C1[gid] = x0*(wt0-wb0) + x1*(wt1-wb1) + x2*(wt2-wb2) + b1[c];
  G1[gid] = x0*wb0 + x1*wb1 + x2*wb2;
}

// ---------------- gather + max + relu ----------------
template<int C>
__global__ void maxrelu_kernel(const float* __restrict__ Ci, const float* __restrict__ G,
                               const int* __restrict__ idx, float* __restrict__ out) {
  int gid = blockIdx.x*256 + threadIdx.x;
  int i = gid / C, c = gid % C;
  float base = Ci[gid];
  float m = -INFINITY;
  for (int j=0; j<KNN; j++) {
    int jj = idx[i*KNN + j];
    m = fmaxf(m, base + G[(long)jj*C + c]);
  }
  out[gid] = fmaxf(m, 0.0f);
}

// ---------------- W2 diff ----------------
__global__ void wd2_kernel(const float* __restrict__ W2, float* __restrict__ Wd) {
  int gid = blockIdx.x*256 + threadIdx.x;   // 64*128
  int d = gid >> 7, c = gid & 127;
  Wd[gid] = W2[d*128+c] - W2[(d+64)*128+c];
}

// ---------------- edge_conv2 precompute ----------------
__global__ void cg2_kernel(const float* __restrict__ h1, const float* __restrict__ W2,
                           const float* __restrict__ Wd, const float* __restrict__ b2,
                           float* __restrict__ C2, float* __restrict__ G2) {
  int gid = blockIdx.x*256 + threadIdx.x;   // 16384*128
  int i = gid >> 7, c = gid & 127;
  float a = 0.f, g = 0.f;
  for (int d=0; d<64; d++) {
    float hv = h1[i*64 + d];
    a += hv * Wd[d*128 + c];
    g += hv * W2[(d+64)*128 + c];
  }
  C2[gid] = a + b2[c];
  G2[gid] = g;
}

// ---------------- fc1 (relu) ----------------
__global__ void fc1_kernel(const float* __restrict__ h2, const float* __restrict__ w,
                           const float* __restrict__ b, float* __restrict__ out) {
  int gid = blockIdx.x*256 + threadIdx.x;   // 16384*128
  int i = gid >> 7, c = gid & 127;
  float a = 0.f;
  for (int d=0; d<128; d++) a += h2[i*128+d] * w[d*128+c];
  out[gid] = fmaxf(a + b[c], 0.0f);
}

// ---------------- fc2 ----------------
__global__ void fc2_kernel(const float* __restrict__ f1, const float* __restrict__ w,
                           const float* __restrict__ b, float* __restrict__ out) {
  int gid = blockIdx.x*256 + threadIdx.x;   // 16384*40
  int i = gid / 40, c = gid - i*40;
  float a = 0.f;
  for (int d=0; d<128; d++) a += f1[i*128+d] * w[d*40+c];
  out[gid] = a + b[c];
}

extern "C" void kernel_launch(void* const* d_in, const int* in_sizes, int n_in,
                              void* d_out, int out_size, void* d_ws, size_t ws_size,
                              hipStream_t stream) {
  (void)in_sizes; (void)n_in; (void)out_size; (void)ws_size;
  const float* x     = (const float*)d_in[0];
  const float* W1    = (const float*)d_in[1];
  const float* b1    = (const float*)d_in[2];
  const float* W2    = (const float*)d_in[3];
  const float* b2    = (const float*)d_in[4];
  const float* fc1_w = (const float*)d_in[5];
  const float* fc1_b = (const float*)d_in[6];
  const float* fc2_w = (const float*)d_in[7];
  const float* fc2_b = (const float*)d_in[8];
  float* out = (float*)d_out;

  // ---- workspace (31.03 MB total, lifetime-disjoint aliasing; proven R12/R17) ----
  char* ws = (char*)d_ws;
  float4* xp4 = (float4*)(ws + 0);          // 262144
  float*  sqh = (float*) (ws + 262144);     // 65536
  int*    idx = (int*)   (ws + 327680);     // 1310720
  float*  Wd2 = (float*) (ws + 1638400);    // 32768
  float*  h1  = (float*) (ws + 1671168);    // 4194304  -> 5865472
  float*  hTt = (float*) (ws + 5865472);    // 4194304  (aliases h2; h2 dead during knn64)
  float*  h2  = (float*) (ws + 5865472);    // 8388608  -> 14254080
  float*  A   = (float*) (ws + 14254080);   // 8388608  -> 22642688
  float*  C1  = A;
  float*  G1  = (float*) (ws + 14254080 + 4194304);
  float*  C2  = A;
  float*  f1  = A;
  float*  G2  = (float*) (ws + 22642688);   // 8388608  -> 31031296
  int*    pi  = (int*)   (ws + 14254080);   // 5.25MB (aliases A; A dead during knn phases)
  float*  pd  = (float*) (ws + 22642688);   // 5.25MB (aliases G2; G2 dead during knn phases)

  pack3_kernel <<<64,   256, 0, stream>>>(x, xp4);
  knn3_wq      <<<1024, 256, 0, stream>>>(xp4, pd, pi);
  knn_merge_kernel<<<64,256, 0, stream>>>(pd, pi, idx);
  cg1_kernel   <<<4096, 256, 0, stream>>>(x, W1, b1, C1, G1);
  maxrelu_kernel<64> <<<4096, 256, 0, stream>>>(C1, G1, idx, h1);
  transpose64_kernel<<<256, 256, 0, stream>>>(h1, hTt);
  sq64_kernel  <<<64,   256, 0, stream>>>(h1, sqh);
  knn64_wq     <<<1024, 256, 0, stream>>>(h1, hTt, sqh, pd, pi);
  knn_merge_kernel<<<64,256, 0, stream>>>(pd, pi, idx);
  wd2_kernel   <<<32,   256, 0, stream>>>(W2, Wd2);
  cg2_kernel   <<<8192, 256, 0, stream>>>(h1, W2, Wd2, b2, C2, G2);
  maxrelu_kernel<128><<<8192, 256, 0, stream>>>(C2, G2, idx, h2);
  fc1_kernel   <<<8192, 256, 0, stream>>>(h2, fc1_w, fc1_b, f1);
  fc2_kernel   <<<2560, 256, 0, stream>>>(f1, fc2_w, fc2_b, out);
}

// Round 19
// 2377.776 us; speedup vs baseline: 57.0046x; 57.0046x over previous
//
#include <hip/hip_runtime.h>
#include <math.h>

#define N_PTS 16384
#define KNN 20
#define NRANGE 4
#define C_RANGE (N_PTS / NRANGE)       // 4096
#define TILES_PER_RANGE (C_RANGE / 64) // 64
#define QCAP 64

// ---------------- pack x + squared norm ----------------
__global__ void pack3_kernel(const float* __restrict__ x, float4* __restrict__ xp) {
  int i = blockIdx.x * blockDim.x + threadIdx.x;
  {
    #pragma clang fp contract(off)
    float a = x[i*3+0], b = x[i*3+1], c = x[i*3+2];
    xp[i] = make_float4(a, b, c, a*a + b*b + c*c);
  }
}

__global__ void sq64_kernel(const float* __restrict__ h, float* __restrict__ sq) {
  int i = blockIdx.x * blockDim.x + threadIdx.x;
  const float4* r = (const float4*)(h + (long)i*64);
  {
    #pragma clang fp contract(off)
    float ax=0.f, ay=0.f, az=0.f, aw=0.f;
    for (int t=0; t<16; t++) {
      float4 v = r[t];
      ax += v.x*v.x; ay += v.y*v.y; az += v.z*v.z; aw += v.w*v.w;
    }
    sq[i] = (ax+ay)+(az+aw);
  }
}

// ---------------- transpose h1 [pt][64] -> hTt [tile][dim][cand64] ----------------
__global__ __launch_bounds__(256) void transpose64_kernel(const float* __restrict__ h,
                                                          float* __restrict__ hTt) {
  __shared__ float t[64][65];
  int b = blockIdx.x;
  int tid = threadIdx.x;
  int r = tid >> 2, c4 = (tid & 3) * 16;
  #pragma unroll
  for (int k = 0; k < 4; k++) {
    float4 v = *(const float4*)(h + (size_t)(b*64+r)*64 + c4 + k*4);
    t[c4+k*4+0][r] = v.x; t[c4+k*4+1][r] = v.y; t[c4+k*4+2][r] = v.z; t[c4+k*4+3][r] = v.w;
  }
  __syncthreads();
  int d = tid >> 2, p4 = (tid & 3) * 16;
  #pragma unroll
  for (int k = 0; k < 4; k++) {
    float4 o;
    o.x = t[d][p4+k*4+0]; o.y = t[d][p4+k*4+1]; o.z = t[d][p4+k*4+2]; o.w = t[d][p4+k*4+3];
    *(float4*)(hTt + ((size_t)b*64 + d)*64 + p4 + k*4) = o;
  }
}

// register top-20: replace current lex-max with (e,ei), rescan for new max.
__device__ __forceinline__ void t20_replace_rescan(float (&rd)[KNN], int (&ri)[KNN],
                                                   float &maxd, int &maxi, int &maxp,
                                                   float e, int ei) {
  #pragma unroll
  for (int k = 0; k < KNN; k++) if (k == maxp) { rd[k] = e; ri[k] = ei; }
  float md = rd[0]; int mi = ri[0]; int mp = 0;
  #pragma unroll
  for (int k = 1; k < KNN; k++) {
    bool g = (rd[k] > md) || (rd[k] == md && ri[k] > mi);
    md = g ? rd[k] : md; mi = g ? ri[k] : mi; mp = g ? k : mp;
  }
  maxd = md; maxi = mi; maxp = mp;
}

// wave-internal fence: drain outstanding LDS ops + stop compiler reordering
#define WAVE_LDS_FENCE() asm volatile("s_waitcnt lgkmcnt(0)" ::: "memory")

// drain: lanes 0..15 fold their query's queued survivors into register lists.
#define WDRAIN(CT0)                                                    \
  do {                                                                 \
    WAVE_LDS_FENCE();                                                  \
    if (l < 16) {                                                      \
      int n = cnt[wv][l]; if (n > QCAP) n = QCAP;                      \
      for (int s = 0; s < n; s++) {                                    \
        float e = qd[wv][l][s]; int ei = (CT0) + (int)qidx[wv][l][s];  \
        if (e < maxd || (e == maxd && ei < maxi))                      \
          t20_replace_rescan(rd, ri, maxd, maxi, maxp, e, ei);         \
      }                                                                \
      cnt[wv][l] = 0;                                                  \
      w19[wv][l] = maxd;                                               \
    }                                                                  \
    WAVE_LDS_FENCE();                                                  \
  } while (0)

// sorted emit: 20 lex-min extractions from the register list
#define EMIT(PD, PI, QBASE)                                            \
  do {                                                                 \
    if (l < 16) {                                                      \
      size_t o = ((size_t)((QBASE) + l)*NRANGE + rg)*KNN;              \
      for (int k = 0; k < KNN; k++) {                                  \
        float md = rd[0]; int mi = ri[0]; int mp = 0;                  \
        _Pragma("unroll")                                              \
        for (int t = 1; t < KNN; t++) {                                \
          bool g = (rd[t] < md) || (rd[t] == md && ri[t] < mi);        \
          md = g ? rd[t] : md; mi = g ? ri[t] : mi; mp = g ? t : mp;   \
        }                                                              \
        PD[o+k] = md; PI[o+k] = mi;                                    \
        _Pragma("unroll")                                              \
        for (int t = 0; t < KNN; t++) if (t == mp) rd[t] = INFINITY;   \
      }                                                                \
    }                                                                  \
  } while (0)

// ---------------- knn D=64: wave-owned queries, register lists ----------------
// Tile-contiguous candidate layout; d-loop partial unroll 8 ONLY — full unroll
// (R18) let the scheduler hoist ~64 loads -> VGPR blowup -> 373 GB scratch traffic.
__global__ __launch_bounds__(256, 4) void knn64_wq(const float* __restrict__ h,
                                                   const float* __restrict__ hTt,
                                                   const float* __restrict__ sq,
                                                   float* __restrict__ pd,
                                                   int* __restrict__ pi) {
  __shared__ float qT[4][64][16];     // [wave][dim][16 queries], 64B rows
  __shared__ float qd[4][16][QCAP];
  __shared__ unsigned char qidx[4][16][QCAP];
  __shared__ float w19[4][16];
  __shared__ int   cnt[4][16];

  int tid = threadIdx.x;
  int wv = tid >> 6;
  int l  = tid & 63;
  int qb = blockIdx.x >> 2, rg = blockIdx.x & 3;
  int q0 = qb*64, c0 = rg*C_RANGE;
  int qw0 = q0 + wv*16;

  float rd[KNN]; int ri[KNN];
  #pragma unroll
  for (int k = 0; k < KNN; k++) { rd[k] = INFINITY; ri[k] = 0x7fffffff; }
  float maxd = INFINITY; int maxi = 0x7fffffff; int maxp = 0;

  if (l < 16) { w19[wv][l] = INFINITY; cnt[wv][l] = 0; }
  {
    int lq = l & 15, m = l >> 4;
    #pragma unroll
    for (int k = 0; k < 4; k++) {
      float4 v = *(const float4*)(h + (size_t)(qw0+lq)*64 + m*16 + k*4);
      qT[wv][m*16+k*4+0][lq] = v.x; qT[wv][m*16+k*4+1][lq] = v.y;
      qT[wv][m*16+k*4+2][lq] = v.z; qT[wv][m*16+k*4+3][lq] = v.w;
    }
  }
  WAVE_LDS_FENCE();

  int qrow0 = (l >> 4) * 4;
  int crow0 = (l & 15) * 4;
  float qsv[4];
  #pragma unroll
  for (int i=0;i<4;i++) qsv[i] = sq[qw0 + qrow0 + i];

  for (int tile = 0; tile < TILES_PER_RANGE; tile++) {
    int ct0 = c0 + tile*64;
    float acc[4][4];
    #pragma unroll
    for (int i=0;i<4;i++)
      #pragma unroll
      for (int j=0;j<4;j++) acc[i][j] = 0.f;

    // tile-contiguous candidates: uniform +64-float stride per dim
    const float* tbase = hTt + ((size_t)(ct0 >> 6))*4096 + crow0;
    #pragma unroll 8
    for (int d = 0; d < 64; d++) {
      float4 cv = *(const float4*)(tbase + d*64);   // 256B dim stride, L1/L2-hot
      float4 qv = *(float4*)&qT[wv][d][qrow0];      // ds_read_b128, imm offset
      acc[0][0] += qv.x*cv.x; acc[0][1] += qv.x*cv.y; acc[0][2] += qv.x*cv.z; acc[0][3] += qv.x*cv.w;
      acc[1][0] += qv.y*cv.x; acc[1][1] += qv.y*cv.y; acc[1][2] += qv.y*cv.z; acc[1][3] += qv.y*cv.w;
      acc[2][0] += qv.z*cv.x; acc[2][1] += qv.z*cv.y; acc[2][2] += qv.z*cv.z; acc[2][3] += qv.z*cv.w;
      acc[3][0] += qv.w*cv.x; acc[3][1] += qv.w*cv.y; acc[3][2] += qv.w*cv.z; acc[3][3] += qv.w*cv.w;
    }

    float csv[4];
    #pragma unroll
    for (int j=0;j<4;j++) csv[j] = sq[ct0+crow0+j];

    // single full-tile push phase (all lanes active)
    #pragma unroll
    for (int i=0;i<4;i++) {
      int lq = qrow0 + i;
      float w = w19[wv][lq];
      #pragma unroll
      for (int j=0;j<4;j++) {
        float dd = (qsv[i] + csv[j]) - 2.0f*acc[i][j];
        if (dd < w) {
          int slot = atomicAdd(&cnt[wv][lq], 1);
          qd[wv][lq][slot] = dd;
          qidx[wv][lq][slot] = (unsigned char)(crow0 + j);
        }
      }
    }
    WDRAIN(ct0);
  }

  EMIT(pd, pi, qw0);
}

// ---------------- knn D=3: wave-owned queries, register lists ----------------
__global__ __launch_bounds__(256, 4) void knn3_wq(const float4* __restrict__ xp,
                                                  float* __restrict__ pd,
                                                  int* __restrict__ pi) {
  __shared__ float qd[4][16][QCAP];
  __shared__ unsigned char qidx[4][16][QCAP];
  __shared__ float w19[4][16];
  __shared__ int   cnt[4][16];

  int tid = threadIdx.x;
  int wv = tid >> 6;
  int l  = tid & 63;
  int qb = blockIdx.x >> 2, rg = blockIdx.x & 3;
  int q0 = qb*64, c0 = rg*C_RANGE;
  int qw0 = q0 + wv*16;

  float rd[KNN]; int ri[KNN];
  #pragma unroll
  for (int k = 0; k < KNN; k++) { rd[k] = INFINITY; ri[k] = 0x7fffffff; }
  float maxd = INFINITY; int maxi = 0x7fffffff; int maxp = 0;

  if (l < 16) { w19[wv][l] = INFINITY; cnt[wv][l] = 0; }
  WAVE_LDS_FENCE();

  int qrow0 = (l >> 4) * 4;
  int crow0 = (l & 15) * 4;
  float4 qv[4];
  #pragma unroll
  for (int i=0;i<4;i++) qv[i] = xp[qw0 + qrow0 + i];

  for (int tile = 0; tile < TILES_PER_RANGE; tile++) {
    int ct0 = c0 + tile*64;
    float4 cv[4];
    #pragma unroll
    for (int j=0;j<4;j++) cv[j] = xp[ct0 + crow0 + j];

    #pragma unroll
    for (int i=0;i<4;i++) {
      int lq = qrow0 + i;
      float w = w19[wv][lq];
      #pragma unroll
      for (int j=0;j<4;j++) {
        float dd = (qv[i].w + cv[j].w)
                 - 2.0f*(qv[i].x*cv[j].x + qv[i].y*cv[j].y + qv[i].z*cv[j].z);
        if (dd < w) {
          int slot = atomicAdd(&cnt[wv][lq], 1);
          qd[wv][lq][slot] = dd;
          qidx[wv][lq][slot] = (unsigned char)(crow0 + j);
        }
      }
    }
    WDRAIN(ct0);
  }

  EMIT(pd, pi, qw0);
}

// ---------------- merge NRANGE sorted partial lists -> top-20 ----------------
__global__ void knn_merge_kernel(const float* __restrict__ pd, const int* __restrict__ pi,
                                 int* __restrict__ out_idx) {
  int qi = blockIdx.x*256 + threadIdx.x;
  const float* bd = pd + (size_t)qi*NRANGE*KNN;
  const int*   bi = pi + (size_t)qi*NRANGE*KNN;
  int ptr[NRANGE];
  #pragma unroll
  for (int r=0;r<NRANGE;r++) ptr[r] = 0;
  for (int k = 0; k < KNN; k++) {
    float best = INFINITY; int besti = 0x7fffffff; int br = 0;
    #pragma unroll
    for (int r = 0; r < NRANGE; r++) {
      float d = bd[r*KNN + ptr[r]];
      int   ii = bi[r*KNN + ptr[r]];
      bool better = (ptr[r] < KNN) && (d < best || (d == best && ii < besti));
      if (better) { best = d; besti = ii; br = r; }
    }
    #pragma unroll
    for (int r=0;r<NRANGE;r++) ptr[r] += (r == br) ? 1 : 0;
    out_idx[qi*KNN + k] = besti;
  }
}

// ---------------- edge_conv1 precompute ----------------
__global__ void cg1_kernel(const float* __restrict__ x, const float* __restrict__ W1,
                           const float* __restrict__ b1,
                           float* __restrict__ C1, float* __restrict__ G1) {
  int gid = blockIdx.x*256 + threadIdx.x;   // 16384*64
  int i = gid >> 6, c = gid & 63;
  float x0 = x[i*3+0], x1 = x[i*3+1], x2 = x[i*3+2];
  float wt0 = W1[0*64+c], wt1 = W1[1*64+c], wt2 = W1[2*64+c];
  float wb0 = W1[3*64+c], wb1 = W1[4*64+c], wb2 = W1[5*64+c];
  C1[gid] = x0*(wt0-wb0) + x1*(wt1-wb1) + x2*(wt2-wb2) + b1[c];
  G1[gid] = x0*wb0 + x1*wb1 + x2*wb2;
}

// ---------------- gather + max + relu ----------------
template<int C>
__global__ void maxrelu_kernel(const float* __restrict__ Ci, const float* __restrict__ G,
                               const int* __restrict__ idx, float* __restrict__ out) {
  int gid = blockIdx.x*256 + threadIdx.x;
  int i = gid / C, c = gid % C;
  float base = Ci[gid];
  float m = -INFINITY;
  for (int j=0; j<KNN; j++) {
    int jj = idx[i*KNN + j];
    m = fmaxf(m, base + G[(long)jj*C + c]);
  }
  out[gid] = fmaxf(m, 0.0f);
}

// ---------------- W2 diff ----------------
__global__ void wd2_kernel(const float* __restrict__ W2, float* __restrict__ Wd) {
  int gid = blockIdx.x*256 + threadIdx.x;   // 64*128
  int d = gid >> 7, c = gid & 127;
  Wd[gid] = W2[d*128+c] - W2[(d+64)*128+c];
}

// ---------------- edge_conv2 precompute ----------------
__global__ void cg2_kernel(const float* __restrict__ h1, const float* __restrict__ W2,
                           const float* __restrict__ Wd, const float* __restrict__ b2,
                           float* __restrict__ C2, float* __restrict__ G2) {
  int gid = blockIdx.x*256 + threadIdx.x;   // 16384*128
  int i = gid >> 7, c = gid & 127;
  float a = 0.f, g = 0.f;
  for (int d=0; d<64; d++) {
    float hv = h1[i*64 + d];
    a += hv * Wd[d*128 + c];
    g += hv * W2[(d+64)*128 + c];
  }
  C2[gid] = a + b2[c];
  G2[gid] = g;
}

// ---------------- fc1 (relu) ----------------
__global__ void fc1_kernel(const float* __restrict__ h2, const float* __restrict__ w,
                           const float* __restrict__ b, float* __restrict__ out) {
  int gid = blockIdx.x*256 + threadIdx.x;   // 16384*128
  int i = gid >> 7, c = gid & 127;
  float a = 0.f;
  for (int d=0; d<128; d++) a += h2[i*128+d] * w[d*128+c];
  out[gid] = fmaxf(a + b[c], 0.0f);
}

// ---------------- fc2 ----------------
__global__ void fc2_kernel(const float* __restrict__ f1, const float* __restrict__ w,
                           const float* __restrict__ b, float* __restrict__ out) {
  int gid = blockIdx.x*256 + threadIdx.x;   // 16384*40
  int i = gid / 40, c = gid - i*40;
  float a = 0.f;
  for (int d=0; d<128; d++) a += f1[i*128+d] * w[d*40+c];
  out[gid] = a + b[c];
}

extern "C" void kernel_launch(void* const* d_in, const int* in_sizes, int n_in,
                              void* d_out, int out_size, void* d_ws, size_t ws_size,
                              hipStream_t stream) {
  (void)in_sizes; (void)n_in; (void)out_size; (void)ws_size;
  const float* x     = (const float*)d_in[0];
  const float* W1    = (const float*)d_in[1];
  const float* b1    = (const float*)d_in[2];
  const float* W2    = (const float*)d_in[3];
  const float* b2    = (const float*)d_in[4];
  const float* fc1_w = (const float*)d_in[5];
  const float* fc1_b = (const float*)d_in[6];
  const float* fc2_w = (const float*)d_in[7];
  const float* fc2_b = (const float*)d_in[8];
  float* out = (float*)d_out;

  // ---- workspace (31.03 MB total, lifetime-disjoint aliasing; proven R12/R17) ----
  char* ws = (char*)d_ws;
  float4* xp4 = (float4*)(ws + 0);          // 262144
  float*  sqh = (float*) (ws + 262144);     // 65536
  int*    idx = (int*)   (ws + 327680);     // 1310720
  float*  Wd2 = (float*) (ws + 1638400);    // 32768
  float*  h1  = (float*) (ws + 1671168);    // 4194304  -> 5865472
  float*  hTt = (float*) (ws + 5865472);    // 4194304  (aliases h2; h2 dead during knn64)
  float*  h2  = (float*) (ws + 5865472);    // 8388608  -> 14254080
  float*  A   = (float*) (ws + 14254080);   // 8388608  -> 22642688
  float*  C1  = A;
  float*  G1  = (float*) (ws + 14254080 + 4194304);
  float*  C2  = A;
  float*  f1  = A;
  float*  G2  = (float*) (ws + 22642688);   // 8388608  -> 31031296
  int*    pi  = (int*)   (ws + 14254080);   // 5.25MB (aliases A; A dead during knn phases)
  float*  pd  = (float*) (ws + 22642688);   // 5.25MB (aliases G2; G2 dead during knn phases)

  pack3_kernel <<<64,   256, 0, stream>>>(x, xp4);
  knn3_wq      <<<1024, 256, 0, stream>>>(xp4, pd, pi);
  knn_merge_kernel<<<64,256, 0, stream>>>(pd, pi, idx);
  cg1_kernel   <<<4096, 256, 0, stream>>>(x, W1, b1, C1, G1);
  maxrelu_kernel<64> <<<4096, 256, 0, stream>>>(C1, G1, idx, h1);
  transpose64_kernel<<<256, 256, 0, stream>>>(h1, hTt);
  sq64_kernel  <<<64,   256, 0, stream>>>(h1, sqh);
  knn64_wq     <<<1024, 256, 0, stream>>>(h1, hTt, sqh, pd, pi);
  knn_merge_kernel<<<64,256, 0, stream>>>(pd, pi, idx);
  wd2_kernel   <<<32,   256, 0, stream>>>(W2, Wd2);
  cg2_kernel   <<<8192, 256, 0, stream>>>(h1, W2, Wd2, b2, C2, G2);
  maxrelu_kernel<128><<<8192, 256, 0, stream>>>(C2, G2, idx, h2);
  fc1_kernel   <<<8192, 256, 0, stream>>>(h2, fc1_w, fc1_b, f1);
  fc2_kernel   <<<2560, 256, 0, stream>>>(f1, fc2_w, fc2_b, out);
}

// Round 20
// 2136.586 us; speedup vs baseline: 63.4396x; 1.1129x over previous
//
#include <hip/hip_runtime.h>
#include <math.h>

#define N_PTS 16384
#define KNN 20
#define NRANGE 4
#define C_RANGE (N_PTS / NRANGE)       // 4096
#define TILES_PER_RANGE (C_RANGE / 64) // 64
#define QCAP 64

// ---------------- pack x + squared norm ----------------
__global__ void pack3_kernel(const float* __restrict__ x, float4* __restrict__ xp) {
  int i = blockIdx.x * blockDim.x + threadIdx.x;
  {
    #pragma clang fp contract(off)
    float a = x[i*3+0], b = x[i*3+1], c = x[i*3+2];
    xp[i] = make_float4(a, b, c, a*a + b*b + c*c);
  }
}

__global__ void sq64_kernel(const float* __restrict__ h, float* __restrict__ sq) {
  int i = blockIdx.x * blockDim.x + threadIdx.x;
  const float4* r = (const float4*)(h + (long)i*64);
  {
    #pragma clang fp contract(off)
    float ax=0.f, ay=0.f, az=0.f, aw=0.f;
    for (int t=0; t<16; t++) {
      float4 v = r[t];
      ax += v.x*v.x; ay += v.y*v.y; az += v.z*v.z; aw += v.w*v.w;
    }
    sq[i] = (ax+ay)+(az+aw);
  }
}

// ---------------- transpose h1 [pt][64] -> hTt [tile][dim][cand64] ----------------
__global__ __launch_bounds__(256) void transpose64_kernel(const float* __restrict__ h,
                                                          float* __restrict__ hTt) {
  __shared__ float t[64][65];
  int b = blockIdx.x;
  int tid = threadIdx.x;
  int r = tid >> 2, c4 = (tid & 3) * 16;
  #pragma unroll
  for (int k = 0; k < 4; k++) {
    float4 v = *(const float4*)(h + (size_t)(b*64+r)*64 + c4 + k*4);
    t[c4+k*4+0][r] = v.x; t[c4+k*4+1][r] = v.y; t[c4+k*4+2][r] = v.z; t[c4+k*4+3][r] = v.w;
  }
  __syncthreads();
  int d = tid >> 2, p4 = (tid & 3) * 16;
  #pragma unroll
  for (int k = 0; k < 4; k++) {
    float4 o;
    o.x = t[d][p4+k*4+0]; o.y = t[d][p4+k*4+1]; o.z = t[d][p4+k*4+2]; o.w = t[d][p4+k*4+3];
    *(float4*)(hTt + ((size_t)b*64 + d)*64 + p4 + k*4) = o;
  }
}

// ---------------- seed thresholds from graph-1 neighbors (exact upper bound) ----------------
// w_seed[i] = max_k dist_h1(i, idx1[i][k]) + pad; pad dominates any cross-kernel
// accumulation-order rounding (<= ~7.7e-6*(sqi+sqj)) so w_seed >= true d_20 always.
__global__ __launch_bounds__(256, 2) void seed64_kernel(const float* __restrict__ h,
                                                        const float* __restrict__ sq,
                                                        const int* __restrict__ idx1,
                                                        float* __restrict__ wsd) {
  int i = blockIdx.x*256 + threadIdx.x;   // 16384
  float4 q4[16];
  const float4* qrow = (const float4*)(h + (size_t)i*64);
  #pragma unroll
  for (int t=0;t<16;t++) q4[t] = qrow[t];
  float sqi = sq[i];
  float wmax = 0.f;
  for (int k=0;k<KNN;k++) {
    int j = idx1[i*KNN+k];
    const float4* crow = (const float4*)(h + (size_t)j*64);
    float acc = 0.f;
    #pragma unroll 4
    for (int t=0;t<16;t++) {
      float4 c = crow[t];
      acc += q4[t].x*c.x; acc += q4[t].y*c.y; acc += q4[t].z*c.z; acc += q4[t].w*c.w;
    }
    float sqj = sq[j];
    float d = (sqi + sqj) - 2.0f*acc;
    d += (sqi + sqj)*3e-5f + 1e-25f;
    wmax = fmaxf(wmax, d);
  }
  wsd[i] = wmax;
}

// register top-20: replace current lex-max with (e,ei), rescan for new max.
__device__ __forceinline__ void t20_replace_rescan(float (&rd)[KNN], int (&ri)[KNN],
                                                   float &maxd, int &maxi, int &maxp,
                                                   float e, int ei) {
  #pragma unroll
  for (int k = 0; k < KNN; k++) if (k == maxp) { rd[k] = e; ri[k] = ei; }
  float md = rd[0]; int mi = ri[0]; int mp = 0;
  #pragma unroll
  for (int k = 1; k < KNN; k++) {
    bool g = (rd[k] > md) || (rd[k] == md && ri[k] > mi);
    md = g ? rd[k] : md; mi = g ? ri[k] : mi; mp = g ? k : mp;
  }
  maxd = md; maxi = mi; maxp = mp;
}

// wave-internal fence: drain outstanding LDS ops + stop compiler reordering
#define WAVE_LDS_FENCE() asm volatile("s_waitcnt lgkmcnt(0)" ::: "memory")

// drain: lanes 0..15 fold their query's queued survivors into register lists.
// WEXPR = new threshold after drain (maxd, optionally clamped by seed bound).
#define WDRAIN(CT0, WEXPR)                                             \
  do {                                                                 \
    WAVE_LDS_FENCE();                                                  \
    if (l < 16) {                                                      \
      int n = cnt[wv][l]; if (n > QCAP) n = QCAP;                      \
      for (int s = 0; s < n; s++) {                                    \
        float e = qd[wv][l][s]; int ei = (CT0) + (int)qidx[wv][l][s];  \
        if (e < maxd || (e == maxd && ei < maxi))                      \
          t20_replace_rescan(rd, ri, maxd, maxi, maxp, e, ei);         \
      }                                                                \
      cnt[wv][l] = 0;                                                  \
      w19[wv][l] = (WEXPR);                                            \
    }                                                                  \
    WAVE_LDS_FENCE();                                                  \
  } while (0)

// sorted emit: 20 lex-min extractions from the register list
#define EMIT(PD, PI, QBASE)                                            \
  do {                                                                 \
    if (l < 16) {                                                      \
      size_t o = ((size_t)((QBASE) + l)*NRANGE + rg)*KNN;              \
      for (int k = 0; k < KNN; k++) {                                  \
        float md = rd[0]; int mi = ri[0]; int mp = 0;                  \
        _Pragma("unroll")                                              \
        for (int t = 1; t < KNN; t++) {                                \
          bool g = (rd[t] < md) || (rd[t] == md && ri[t] < mi);        \
          md = g ? rd[t] : md; mi = g ? ri[t] : mi; mp = g ? t : mp;   \
        }                                                              \
        PD[o+k] = md; PI[o+k] = mi;                                    \
        _Pragma("unroll")                                              \
        for (int t = 0; t < KNN; t++) if (t == mp) rd[t] = INFINITY;   \
      }                                                                \
    }                                                                  \
  } while (0)

// ---------------- knn D=64: seeded thresholds, register lists ----------------
__global__ __launch_bounds__(256, 4) void knn64_wq(const float* __restrict__ h,
                                                   const float* __restrict__ hTt,
                                                   const float* __restrict__ sq,
                                                   const float* __restrict__ wsd,
                                                   float* __restrict__ pd,
                                                   int* __restrict__ pi) {
  __shared__ float qT[4][64][16];     // [wave][dim][16 queries], 64B rows
  __shared__ float qd[4][16][QCAP];
  __shared__ unsigned char qidx[4][16][QCAP];
  __shared__ float w19[4][16];
  __shared__ int   cnt[4][16];

  int tid = threadIdx.x;
  int wv = tid >> 6;
  int l  = tid & 63;
  int qb = blockIdx.x >> 2, rg = blockIdx.x & 3;
  int q0 = qb*64, c0 = rg*C_RANGE;
  int qw0 = q0 + wv*16;

  float rd[KNN]; int ri[KNN];
  #pragma unroll
  for (int k = 0; k < KNN; k++) { rd[k] = INFINITY; ri[k] = 0x7fffffff; }
  float maxd = INFINITY; int maxi = 0x7fffffff; int maxp = 0;

  float wsv = INFINITY;
  if (l < 16) { wsv = wsd[qw0 + l]; w19[wv][l] = wsv; cnt[wv][l] = 0; }
  {
    int lq = l & 15, m = l >> 4;
    #pragma unroll
    for (int k = 0; k < 4; k++) {
      float4 v = *(const float4*)(h + (size_t)(qw0+lq)*64 + m*16 + k*4);
      qT[wv][m*16+k*4+0][lq] = v.x; qT[wv][m*16+k*4+1][lq] = v.y;
      qT[wv][m*16+k*4+2][lq] = v.z; qT[wv][m*16+k*4+3][lq] = v.w;
    }
  }
  WAVE_LDS_FENCE();

  int qrow0 = (l >> 4) * 4;
  int crow0 = (l & 15) * 4;
  float qsv[4];
  #pragma unroll
  for (int i=0;i<4;i++) qsv[i] = sq[qw0 + qrow0 + i];

  for (int tile = 0; tile < TILES_PER_RANGE; tile++) {
    int ct0 = c0 + tile*64;
    float acc[4][4];
    #pragma unroll
    for (int i=0;i<4;i++)
      #pragma unroll
      for (int j=0;j<4;j++) acc[i][j] = 0.f;

    // tile-contiguous candidates: uniform +64-float stride per dim
    const float* tbase = hTt + ((size_t)(ct0 >> 6))*4096 + crow0;
    #pragma unroll 8
    for (int d = 0; d < 64; d++) {
      float4 cv = *(const float4*)(tbase + d*64);   // 256B dim stride, L1/L2-hot
      float4 qv = *(float4*)&qT[wv][d][qrow0];      // ds_read_b128, imm offset
      acc[0][0] += qv.x*cv.x; acc[0][1] += qv.x*cv.y; acc[0][2] += qv.x*cv.z; acc[0][3] += qv.x*cv.w;
      acc[1][0] += qv.y*cv.x; acc[1][1] += qv.y*cv.y; acc[1][2] += qv.y*cv.z; acc[1][3] += qv.y*cv.w;
      acc[2][0] += qv.z*cv.x; acc[2][1] += qv.z*cv.y; acc[2][2] += qv.z*cv.z; acc[2][3] += qv.z*cv.w;
      acc[3][0] += qv.w*cv.x; acc[3][1] += qv.w*cv.y; acc[3][2] += qv.w*cv.z; acc[3][3] += qv.w*cv.w;
    }

    float csv[4];
    #pragma unroll
    for (int j=0;j<4;j++) csv[j] = sq[ct0+crow0+j];

    // push phase: lex-safe <= filter (seed bound is an upper bound; ties at the
    // current 20th resolved exactly at drain). <=16 lanes x 4 cands = QCAP max.
    #pragma unroll
    for (int i=0;i<4;i++) {
      int lq = qrow0 + i;
      float w = w19[wv][lq];
      #pragma unroll
      for (int j=0;j<4;j++) {
        float dd = (qsv[i] + csv[j]) - 2.0f*acc[i][j];
        if (dd <= w) {
          int slot = atomicAdd(&cnt[wv][lq], 1);
          qd[wv][lq][slot] = dd;
          qidx[wv][lq][slot] = (unsigned char)(crow0 + j);
        }
      }
    }
    WDRAIN(ct0, fminf(maxd, wsv));
  }

  EMIT(pd, pi, qw0);
}

// ---------------- knn D=3: wave-owned queries, register lists ----------------
__global__ __launch_bounds__(256, 4) void knn3_wq(const float4* __restrict__ xp,
                                                  float* __restrict__ pd,
                                                  int* __restrict__ pi) {
  __shared__ float qd[4][16][QCAP];
  __shared__ unsigned char qidx[4][16][QCAP];
  __shared__ float w19[4][16];
  __shared__ int   cnt[4][16];

  int tid = threadIdx.x;
  int wv = tid >> 6;
  int l  = tid & 63;
  int qb = blockIdx.x >> 2, rg = blockIdx.x & 3;
  int q0 = qb*64, c0 = rg*C_RANGE;
  int qw0 = q0 + wv*16;

  float rd[KNN]; int ri[KNN];
  #pragma unroll
  for (int k = 0; k < KNN; k++) { rd[k] = INFINITY; ri[k] = 0x7fffffff; }
  float maxd = INFINITY; int maxi = 0x7fffffff; int maxp = 0;

  if (l < 16) { w19[wv][l] = INFINITY; cnt[wv][l] = 0; }
  WAVE_LDS_FENCE();

  int qrow0 = (l >> 4) * 4;
  int crow0 = (l & 15) * 4;
  float4 qv[4];
  #pragma unroll
  for (int i=0;i<4;i++) qv[i] = xp[qw0 + qrow0 + i];

  for (int tile = 0; tile < TILES_PER_RANGE; tile++) {
    int ct0 = c0 + tile*64;
    float4 cv[4];
    #pragma unroll
    for (int j=0;j<4;j++) cv[j] = xp[ct0 + crow0 + j];

    #pragma unroll
    for (int i=0;i<4;i++) {
      int lq = qrow0 + i;
      float w = w19[wv][lq];
      #pragma unroll
      for (int j=0;j<4;j++) {
        float dd = (qv[i].w + cv[j].w)
                 - 2.0f*(qv[i].x*cv[j].x + qv[i].y*cv[j].y + qv[i].z*cv[j].z);
        if (dd < w) {
          int slot = atomicAdd(&cnt[wv][lq], 1);
          qd[wv][lq][slot] = dd;
          qidx[wv][lq][slot] = (unsigned char)(crow0 + j);
        }
      }
    }
    WDRAIN(ct0, maxd);
  }

  EMIT(pd, pi, qw0);
}

// ---------------- merge NRANGE sorted partial lists -> top-20 ----------------
__global__ void knn_merge_kernel(const float* __restrict__ pd, const int* __restrict__ pi,
                                 int* __restrict__ out_idx) {
  int qi = blockIdx.x*256 + threadIdx.x;
  const float* bd = pd + (size_t)qi*NRANGE*KNN;
  const int*   bi = pi + (size_t)qi*NRANGE*KNN;
  int ptr[NRANGE];
  #pragma unroll
  for (int r=0;r<NRANGE;r++) ptr[r] = 0;
  for (int k = 0; k < KNN; k++) {
    float best = INFINITY; int besti = 0x7fffffff; int br = 0;
    #pragma unroll
    for (int r = 0; r < NRANGE; r++) {
      float d = bd[r*KNN + ptr[r]];
      int   ii = bi[r*KNN + ptr[r]];
      bool better = (ptr[r] < KNN) && (d < best || (d == best && ii < besti));
      if (better) { best = d; besti = ii; br = r; }
    }
    #pragma unroll
    for (int r=0;r<NRANGE;r++) ptr[r] += (r == br) ? 1 : 0;
    out_idx[qi*KNN + k] = besti;
  }
}

// ---------------- edge_conv1 precompute ----------------
__global__ void cg1_kernel(const float* __restrict__ x, const float* __restrict__ W1,
                           const float* __restrict__ b1,
                           float* __restrict__ C1, float* __restrict__ G1) {
  int gid = blockIdx.x*256 + threadIdx.x;   // 16384*64
  int i = gid >> 6, c = gid & 63;
  float x0 = x[i*3+0], x1 = x[i*3+1], x2 = x[i*3+2];
  float wt0 = W1[0*64+c], wt1 = W1[1*64+c], wt2 = W1[2*64+c];
  float wb0 = W1[3*64+c], wb1 = W1[4*64+c], wb2 = W1[5*64+c];
  C1[gid] = x0*(wt0-wb0) + x1*(wt1-wb1) + x2*(wt2-wb2) + b1[c];
  G1[gid] = x0*wb0 + x1*wb1 + x2*wb2;
}

// ---------------- gather + max + relu ----------------
template<int C>
__global__ void maxrelu_kernel(const float* __restrict__ Ci, const float* __restrict__ G,
                               const int* __restrict__ idx, float* __restrict__ out) {
  int gid = blockIdx.x*256 + threadIdx.x;
  int i = gid / C, c = gid % C;
  float base = Ci[gid];
  float m = -INFINITY;
  for (int j=0; j<KNN; j++) {
    int jj = idx[i*KNN + j];
    m = fmaxf(m, base + G[(long)jj*C + c]);
  }
  out[gid] = fmaxf(m, 0.0f);
}

// ---------------- W2 diff ----------------
__global__ void wd2_kernel(const float* __restrict__ W2, float* __restrict__ Wd) {
  int gid = blockIdx.x*256 + threadIdx.x;   // 64*128
  int d = gid >> 7, c = gid & 127;
  Wd[gid] = W2[d*128+c] - W2[(d+64)*128+c];
}

// ---------------- edge_conv2 precompute ----------------
__global__ void cg2_kernel(const float* __restrict__ h1, const float* __restrict__ W2,
                           const float* __restrict__ Wd, const float* __restrict__ b2,
                           float* __restrict__ C2, float* __restrict__ G2) {
  int gid = blockIdx.x*256 + threadIdx.x;   // 16384*128
  int i = gid >> 7, c = gid & 127;
  float a = 0.f, g = 0.f;
  for (int d=0; d<64; d++) {
    float hv = h1[i*64 + d];
    a += hv * Wd[d*128 + c];
    g += hv * W2[(d+64)*128 + c];
  }
  C2[gid] = a + b2[c];
  G2[gid] = g;
}

// ---------------- fc1 (relu) ----------------
__global__ void fc1_kernel(const float* __restrict__ h2, const float* __restrict__ w,
                           const float* __restrict__ b, float* __restrict__ out) {
  int gid = blockIdx.x*256 + threadIdx.x;   // 16384*128
  int i = gid >> 7, c = gid & 127;
  float a = 0.f;
  for (int d=0; d<128; d++) a += h2[i*128+d] * w[d*128+c];
  out[gid] = fmaxf(a + b[c], 0.0f);
}

// ---------------- fc2 ----------------
__global__ void fc2_kernel(const float* __restrict__ f1, const float* __restrict__ w,
                           const float* __restrict__ b, float* __restrict__ out) {
  int gid = blockIdx.x*256 + threadIdx.x;   // 16384*40
  int i = gid / 40, c = gid - i*40;
  float a = 0.f;
  for (int d=0; d<128; d++) a += f1[i*128+d] * w[d*40+c];
  out[gid] = a + b[c];
}

extern "C" void kernel_launch(void* const* d_in, const int* in_sizes, int n_in,
                              void* d_out, int out_size, void* d_ws, size_t ws_size,
                              hipStream_t stream) {
  (void)in_sizes; (void)n_in; (void)out_size; (void)ws_size;
  const float* x     = (const float*)d_in[0];
  const float* W1    = (const float*)d_in[1];
  const float* b1    = (const float*)d_in[2];
  const float* W2    = (const float*)d_in[3];
  const float* b2    = (const float*)d_in[4];
  const float* fc1_w = (const float*)d_in[5];
  const float* fc1_b = (const float*)d_in[6];
  const float* fc2_w = (const float*)d_in[7];
  const float* fc2_b = (const float*)d_in[8];
  float* out = (float*)d_out;

  // ---- workspace (31.03 MB total, lifetime-disjoint aliasing; proven R12/R17/R19) ----
  // wsd (64 KB) sits in the h2 region past hTt: dead until maxrelu128 writes h2.
  char* ws = (char*)d_ws;
  float4* xp4 = (float4*)(ws + 0);          // 262144
  float*  sqh = (float*) (ws + 262144);     // 65536
  int*    idx = (int*)   (ws + 327680);     // 1310720
  float*  Wd2 = (float*) (ws + 1638400);    // 32768
  float*  h1  = (float*) (ws + 1671168);    // 4194304  -> 5865472
  float*  hTt = (float*) (ws + 5865472);    // 4194304  -> 10059776 (aliases h2-head)
  float*  wsd = (float*) (ws + 10059776);   // 65536    (aliases h2-tail; dead then)
  float*  h2  = (float*) (ws + 5865472);    // 8388608  -> 14254080
  float*  A   = (float*) (ws + 14254080);   // 8388608  -> 22642688
  float*  C1  = A;
  float*  G1  = (float*) (ws + 14254080 + 4194304);
  float*  C2  = A;
  float*  f1  = A;
  float*  G2  = (float*) (ws + 22642688);   // 8388608  -> 31031296
  int*    pi  = (int*)   (ws + 14254080);   // 5.25MB (aliases A; A dead during knn phases)
  float*  pd  = (float*) (ws + 22642688);   // 5.25MB (aliases G2; G2 dead during knn phases)

  pack3_kernel <<<64,   256, 0, stream>>>(x, xp4);
  knn3_wq      <<<1024, 256, 0, stream>>>(xp4, pd, pi);
  knn_merge_kernel<<<64,256, 0, stream>>>(pd, pi, idx);
  cg1_kernel   <<<4096, 256, 0, stream>>>(x, W1, b1, C1, G1);
  maxrelu_kernel<64> <<<4096, 256, 0, stream>>>(C1, G1, idx, h1);
  transpose64_kernel<<<256, 256, 0, stream>>>(h1, hTt);
  sq64_kernel  <<<64,   256, 0, stream>>>(h1, sqh);
  seed64_kernel<<<64,   256, 0, stream>>>(h1, sqh, idx, wsd);
  knn64_wq     <<<1024, 256, 0, stream>>>(h1, hTt, sqh, wsd, pd, pi);
  knn_merge_kernel<<<64,256, 0, stream>>>(pd, pi, idx);
  wd2_kernel   <<<32,   256, 0, stream>>>(W2, Wd2);
  cg2_kernel   <<<8192, 256, 0, stream>>>(h1, W2, Wd2, b2, C2, G2);
  maxrelu_kernel<128><<<8192, 256, 0, stream>>>(C2, G2, idx, h2);
  fc1_kernel   <<<8192, 256, 0, stream>>>(h2, fc1_w, fc1_b, f1);
  fc2_kernel   <<<2560, 256, 0, stream>>>(f1, fc2_w, fc2_b, out);
}

// Round 21
// 1787.539 us; speedup vs baseline: 75.8273x; 1.1953x over previous
//
#include <hip/hip_runtime.h>
#include <math.h>

#define N_PTS 16384
#define KNN 20
#define NRANGE 4
#define C_RANGE (N_PTS / NRANGE)       // 4096
#define SUPER_PER_RANGE (C_RANGE / 128) // 32
#define QCAP 64

// ---------------- pack x + squared norm ----------------
__global__ void pack3_kernel(const float* __restrict__ x, float4* __restrict__ xp) {
  int i = blockIdx.x * blockDim.x + threadIdx.x;
  {
    #pragma clang fp contract(off)
    float a = x[i*3+0], b = x[i*3+1], c = x[i*3+2];
    xp[i] = make_float4(a, b, c, a*a + b*b + c*c);
  }
}

__global__ void sq64_kernel(const float* __restrict__ h, float* __restrict__ sq) {
  int i = blockIdx.x * blockDim.x + threadIdx.x;
  const float4* r = (const float4*)(h + (long)i*64);
  {
    #pragma clang fp contract(off)
    float ax=0.f, ay=0.f, az=0.f, aw=0.f;
    for (int t=0; t<16; t++) {
      float4 v = r[t];
      ax += v.x*v.x; ay += v.y*v.y; az += v.z*v.z; aw += v.w*v.w;
    }
    sq[i] = (ax+ay)+(az+aw);
  }
}

// ---------------- transpose h1 [pt][64] -> hTt [tile][dim][cand64] ----------------
__global__ __launch_bounds__(256) void transpose64_kernel(const float* __restrict__ h,
                                                          float* __restrict__ hTt) {
  __shared__ float t[64][65];
  int b = blockIdx.x;
  int tid = threadIdx.x;
  int r = tid >> 2, c4 = (tid & 3) * 16;
  #pragma unroll
  for (int k = 0; k < 4; k++) {
    float4 v = *(const float4*)(h + (size_t)(b*64+r)*64 + c4 + k*4);
    t[c4+k*4+0][r] = v.x; t[c4+k*4+1][r] = v.y; t[c4+k*4+2][r] = v.z; t[c4+k*4+3][r] = v.w;
  }
  __syncthreads();
  int d = tid >> 2, p4 = (tid & 3) * 16;
  #pragma unroll
  for (int k = 0; k < 4; k++) {
    float4 o;
    o.x = t[d][p4+k*4+0]; o.y = t[d][p4+k*4+1]; o.z = t[d][p4+k*4+2]; o.w = t[d][p4+k*4+3];
    *(float4*)(hTt + ((size_t)b*64 + d)*64 + p4 + k*4) = o;
  }
}

// ---------------- seed thresholds from graph-1 neighbors (exact upper bound) ----------------
__global__ __launch_bounds__(256, 2) void seed64_kernel(const float* __restrict__ h,
                                                        const float* __restrict__ sq,
                                                        const int* __restrict__ idx1,
                                                        float* __restrict__ wsd) {
  int i = blockIdx.x*256 + threadIdx.x;   // 16384
  float4 q4[16];
  const float4* qrow = (const float4*)(h + (size_t)i*64);
  #pragma unroll
  for (int t=0;t<16;t++) q4[t] = qrow[t];
  float sqi = sq[i];
  float wmax = 0.f;
  for (int k=0;k<KNN;k++) {
    int j = idx1[i*KNN+k];
    const float4* crow = (const float4*)(h + (size_t)j*64);
    float acc = 0.f;
    #pragma unroll 4
    for (int t=0;t<16;t++) {
      float4 c = crow[t];
      acc += q4[t].x*c.x; acc += q4[t].y*c.y; acc += q4[t].z*c.z; acc += q4[t].w*c.w;
    }
    float sqj = sq[j];
    float d = (sqi + sqj) - 2.0f*acc;
    d += (sqi + sqj)*3e-5f + 1e-25f;
    wmax = fmaxf(wmax, d);
  }
  wsd[i] = wmax;
}

// register top-20: replace current lex-max with (e,ei), rescan for new max.
__device__ __forceinline__ void t20_replace_rescan(float (&rd)[KNN], int (&ri)[KNN],
                                                   float &maxd, int &maxi, int &maxp,
                                                   float e, int ei) {
  #pragma unroll
  for (int k = 0; k < KNN; k++) if (k == maxp) { rd[k] = e; ri[k] = ei; }
  float md = rd[0]; int mi = ri[0]; int mp = 0;
  #pragma unroll
  for (int k = 1; k < KNN; k++) {
    bool g = (rd[k] > md) || (rd[k] == md && ri[k] > mi);
    md = g ? rd[k] : md; mi = g ? ri[k] : mi; mp = g ? k : mp;
  }
  maxd = md; maxi = mi; maxp = mp;
}

// wave-internal fence: drain outstanding LDS ops + stop compiler reordering
#define WAVE_LDS_FENCE() asm volatile("s_waitcnt lgkmcnt(0)" ::: "memory")

// drain: lanes 0..15 fold their query's queued survivors into register lists.
#define WDRAIN(CT0, WEXPR)                                             \
  do {                                                                 \
    WAVE_LDS_FENCE();                                                  \
    if (l < 16) {                                                      \
      int n = cnt[wv][l]; if (n > QCAP) n = QCAP;                      \
      for (int s = 0; s < n; s++) {                                    \
        float e = qd[wv][l][s]; int ei = (CT0) + (int)qidx[wv][l][s];  \
        if (e < maxd || (e == maxd && ei < maxi))                      \
          t20_replace_rescan(rd, ri, maxd, maxi, maxp, e, ei);         \
      }                                                                \
      cnt[wv][l] = 0;                                                  \
      w19[wv][l] = (WEXPR);                                            \
    }                                                                  \
    WAVE_LDS_FENCE();                                                  \
  } while (0)

// sorted emit: 20 lex-min extractions from the register list
#define EMIT(PD, PI, QBASE)                                            \
  do {                                                                 \
    if (l < 16) {                                                      \
      size_t o = ((size_t)((QBASE) + l)*NRANGE + rg)*KNN;              \
      for (int k = 0; k < KNN; k++) {                                  \
        float md = rd[0]; int mi = ri[0]; int mp = 0;                  \
        _Pragma("unroll")                                              \
        for (int t = 1; t < KNN; t++) {                                \
          bool g = (rd[t] < md) || (rd[t] == md && ri[t] < mi);        \
          md = g ? rd[t] : md; mi = g ? ri[t] : mi; mp = g ? t : mp;   \
        }                                                              \
        PD[o+k] = md; PI[o+k] = mi;                                    \
        _Pragma("unroll")                                              \
        for (int t = 0; t < KNN; t++) if (t == mp) rd[t] = INFINITY;   \
      }                                                                \
    }                                                                  \
  } while (0)

// ---------------- knn D=64: 8q x 4c register tile over 128-cand super-tiles ----------------
// Lane covers 8 queries x 4 cands; tilesel = which 64-cand half it loads.
// Push split by tilesel half + drain each -> per query per half <= 16 lanes x 4
// = 64 = QCAP (structural). Seeded thresholds from graph-1 (exact upper bound).
__global__ __launch_bounds__(256, 4) void knn64_wq(const float* __restrict__ h,
                                                   const float* __restrict__ hTt,
                                                   const float* __restrict__ sq,
                                                   const float* __restrict__ wsd,
                                                   float* __restrict__ pd,
                                                   int* __restrict__ pi) {
  __shared__ float qT[4][64][16];     // [wave][dim][16 queries], 64B rows
  __shared__ float qd[4][16][QCAP];
  __shared__ unsigned char qidx[4][16][QCAP];
  __shared__ float w19[4][16];
  __shared__ int   cnt[4][16];

  int tid = threadIdx.x;
  int wv = tid >> 6;
  int l  = tid & 63;
  int qb = blockIdx.x >> 2, rg = blockIdx.x & 3;
  int q0 = qb*64, c0 = rg*C_RANGE;
  int qw0 = q0 + wv*16;

  float rd[KNN]; int ri[KNN];
  #pragma unroll
  for (int k = 0; k < KNN; k++) { rd[k] = INFINITY; ri[k] = 0x7fffffff; }
  float maxd = INFINITY; int maxi = 0x7fffffff; int maxp = 0;

  float wsv = INFINITY;
  if (l < 16) { wsv = wsd[qw0 + l]; w19[wv][l] = wsv; cnt[wv][l] = 0; }
  {
    int lq = l & 15, m = l >> 4;
    #pragma unroll
    for (int k = 0; k < 4; k++) {
      float4 v = *(const float4*)(h + (size_t)(qw0+lq)*64 + m*16 + k*4);
      qT[wv][m*16+k*4+0][lq] = v.x; qT[wv][m*16+k*4+1][lq] = v.y;
      qT[wv][m*16+k*4+2][lq] = v.z; qT[wv][m*16+k*4+3][lq] = v.w;
    }
  }
  WAVE_LDS_FENCE();

  int qrow0  = (l >> 5) * 8;          // 0 or 8: lane's 8 queries
  int cg     = l & 31;
  int tilesel = cg >> 4;              // which 64-cand half of the super-tile
  int crow0  = (cg & 15) * 4;         // cand base within that half
  float qsv[8];
  #pragma unroll
  for (int i=0;i<8;i++) qsv[i] = sq[qw0 + qrow0 + i];

  for (int st = 0; st < SUPER_PER_RANGE; st++) {
    int ct0 = c0 + st*128;            // super-tile global base
    float acc[8][4];
    #pragma unroll
    for (int i=0;i<8;i++)
      #pragma unroll
      for (int j=0;j<4;j++) acc[i][j] = 0.f;

    const float* tbase = hTt + ((size_t)(ct0 >> 6) + tilesel)*4096 + crow0;
    #pragma unroll 4
    for (int d = 0; d < 64; d++) {
      float4 cv  = *(const float4*)(tbase + d*64);     // 1 load per 32 FMA
      float4 qv0 = *(float4*)&qT[wv][d][qrow0];        // ds_read_b128
      float4 qv1 = *(float4*)&qT[wv][d][qrow0+4];
      acc[0][0] += qv0.x*cv.x; acc[0][1] += qv0.x*cv.y; acc[0][2] += qv0.x*cv.z; acc[0][3] += qv0.x*cv.w;
      acc[1][0] += qv0.y*cv.x; acc[1][1] += qv0.y*cv.y; acc[1][2] += qv0.y*cv.z; acc[1][3] += qv0.y*cv.w;
      acc[2][0] += qv0.z*cv.x; acc[2][1] += qv0.z*cv.y; acc[2][2] += qv0.z*cv.z; acc[2][3] += qv0.z*cv.w;
      acc[3][0] += qv0.w*cv.x; acc[3][1] += qv0.w*cv.y; acc[3][2] += qv0.w*cv.z; acc[3][3] += qv0.w*cv.w;
      acc[4][0] += qv1.x*cv.x; acc[4][1] += qv1.x*cv.y; acc[4][2] += qv1.x*cv.z; acc[4][3] += qv1.x*cv.w;
      acc[5][0] += qv1.y*cv.x; acc[5][1] += qv1.y*cv.y; acc[5][2] += qv1.y*cv.z; acc[5][3] += qv1.y*cv.w;
      acc[6][0] += qv1.z*cv.x; acc[6][1] += qv1.z*cv.y; acc[6][2] += qv1.z*cv.z; acc[6][3] += qv1.z*cv.w;
      acc[7][0] += qv1.w*cv.x; acc[7][1] += qv1.w*cv.y; acc[7][2] += qv1.w*cv.z; acc[7][3] += qv1.w*cv.w;
    }

    int clocal = tilesel*64 + crow0;  // local offset within super-tile (<128)
    float csv[4];
    #pragma unroll
    for (int j=0;j<4;j++) csv[j] = sq[ct0 + clocal + j];

    // half A push (tilesel==0 lanes), drain; half B push, drain.
    #pragma unroll
    for (int half = 0; half < 2; half++) {
      if (tilesel == half) {
        #pragma unroll
        for (int i=0;i<8;i++) {
          int lq = qrow0 + i;
          float w = w19[wv][lq];
          #pragma unroll
          for (int j=0;j<4;j++) {
            float dd = (qsv[i] + csv[j]) - 2.0f*acc[i][j];
            if (dd <= w) {
              int slot = atomicAdd(&cnt[wv][lq], 1);
              qd[wv][lq][slot] = dd;
              qidx[wv][lq][slot] = (unsigned char)(clocal + j);
            }
          }
        }
      }
      WDRAIN(ct0, fminf(maxd, wsv));
    }
  }

  EMIT(pd, pi, qw0);
}

// ---------------- knn D=3: wave-owned queries, register lists (R19 proven) ----------------
__global__ __launch_bounds__(256, 4) void knn3_wq(const float4* __restrict__ xp,
                                                  float* __restrict__ pd,
                                                  int* __restrict__ pi) {
  __shared__ float qd[4][16][QCAP];
  __shared__ unsigned char qidx[4][16][QCAP];
  __shared__ float w19[4][16];
  __shared__ int   cnt[4][16];

  int tid = threadIdx.x;
  int wv = tid >> 6;
  int l  = tid & 63;
  int qb = blockIdx.x >> 2, rg = blockIdx.x & 3;
  int q0 = qb*64, c0 = rg*C_RANGE;
  int qw0 = q0 + wv*16;

  float rd[KNN]; int ri[KNN];
  #pragma unroll
  for (int k = 0; k < KNN; k++) { rd[k] = INFINITY; ri[k] = 0x7fffffff; }
  float maxd = INFINITY; int maxi = 0x7fffffff; int maxp = 0;

  if (l < 16) { w19[wv][l] = INFINITY; cnt[wv][l] = 0; }
  WAVE_LDS_FENCE();

  int qrow0 = (l >> 4) * 4;
  int crow0 = (l & 15) * 4;
  float4 qv[4];
  #pragma unroll
  for (int i=0;i<4;i++) qv[i] = xp[qw0 + qrow0 + i];

  for (int tile = 0; tile < C_RANGE/64; tile++) {
    int ct0 = c0 + tile*64;
    float4 cv[4];
    #pragma unroll
    for (int j=0;j<4;j++) cv[j] = xp[ct0 + crow0 + j];

    #pragma unroll
    for (int i=0;i<4;i++) {
      int lq = qrow0 + i;
      float w = w19[wv][lq];
      #pragma unroll
      for (int j=0;j<4;j++) {
        float dd = (qv[i].w + cv[j].w)
                 - 2.0f*(qv[i].x*cv[j].x + qv[i].y*cv[j].y + qv[i].z*cv[j].z);
        if (dd < w) {
          int slot = atomicAdd(&cnt[wv][lq], 1);
          qd[wv][lq][slot] = dd;
          qidx[wv][lq][slot] = (unsigned char)(crow0 + j);
        }
      }
    }
    WDRAIN(ct0, maxd);
  }

  EMIT(pd, pi, qw0);
}

// ---------------- merge NRANGE sorted partial lists -> top-20 ----------------
__global__ void knn_merge_kernel(const float* __restrict__ pd, const int* __restrict__ pi,
                                 int* __restrict__ out_idx) {
  int qi = blockIdx.x*256 + threadIdx.x;
  const float* bd = pd + (size_t)qi*NRANGE*KNN;
  const int*   bi = pi + (size_t)qi*NRANGE*KNN;
  int ptr[NRANGE];
  #pragma unroll
  for (int r=0;r<NRANGE;r++) ptr[r] = 0;
  for (int k = 0; k < KNN; k++) {
    float best = INFINITY; int besti = 0x7fffffff; int br = 0;
    #pragma unroll
    for (int r = 0; r < NRANGE; r++) {
      float d = bd[r*KNN + ptr[r]];
      int   ii = bi[r*KNN + ptr[r]];
      bool better = (ptr[r] < KNN) && (d < best || (d == best && ii < besti));
      if (better) { best = d; besti = ii; br = r; }
    }
    #pragma unroll
    for (int r=0;r<NRANGE;r++) ptr[r] += (r == br) ? 1 : 0;
    out_idx[qi*KNN + k] = besti;
  }
}

// ---------------- edge_conv1 precompute ----------------
__global__ void cg1_kernel(const float* __restrict__ x, const float* __restrict__ W1,
                           const float* __restrict__ b1,
                           float* __restrict__ C1, float* __restrict__ G1) {
  int gid = blockIdx.x*256 + threadIdx.x;   // 16384*64
  int i = gid >> 6, c = gid & 63;
  float x0 = x[i*3+0], x1 = x[i*3+1], x2 = x[i*3+2];
  float wt0 = W1[0*64+c], wt1 = W1[1*64+c], wt2 = W1[2*64+c];
  float wb0 = W1[3*64+c], wb1 = W1[4*64+c], wb2 = W1[5*64+c];
  C1[gid] = x0*(wt0-wb0) + x1*(wt1-wb1) + x2*(wt2-wb2) + b1[c];
  G1[gid] = x0*wb0 + x1*wb1 + x2*wb2;
}

// ---------------- gather + max + relu ----------------
template<int C>
__global__ void maxrelu_kernel(const float* __restrict__ Ci, const float* __restrict__ G,
                               const int* __restrict__ idx, float* __restrict__ out) {
  int gid = blockIdx.x*256 + threadIdx.x;
  int i = gid / C, c = gid % C;
  float base = Ci[gid];
  float m = -INFINITY;
  for (int j=0; j<KNN; j++) {
    int jj = idx[i*KNN + j];
    m = fmaxf(m, base + G[(long)jj*C + c]);
  }
  out[gid] = fmaxf(m, 0.0f);
}

// ---------------- W2 diff ----------------
__global__ void wd2_kernel(const float* __restrict__ W2, float* __restrict__ Wd) {
  int gid = blockIdx.x*256 + threadIdx.x;   // 64*128
  int d = gid >> 7, c = gid & 127;
  Wd[gid] = W2[d*128+c] - W2[(d+64)*128+c];
}

// ---------------- edge_conv2 precompute ----------------
__global__ void cg2_kernel(const float* __restrict__ h1, const float* __restrict__ W2,
                           const float* __restrict__ Wd, const float* __restrict__ b2,
                           float* __restrict__ C2, float* __restrict__ G2) {
  int gid = blockIdx.x*256 + threadIdx.x;   // 16384*128
  int i = gid >> 7, c = gid & 127;
  float a = 0.f, g = 0.f;
  for (int d=0; d<64; d++) {
    float hv = h1[i*64 + d];
    a += hv * Wd[d*128 + c];
    g += hv * W2[(d+64)*128 + c];
  }
  C2[gid] = a + b2[c];
  G2[gid] = g;
}

// ---------------- fc1 (relu) ----------------
__global__ void fc1_kernel(const float* __restrict__ h2, const float* __restrict__ w,
                           const float* __restrict__ b, float* __restrict__ out) {
  int gid = blockIdx.x*256 + threadIdx.x;   // 16384*128
  int i = gid >> 7, c = gid & 127;
  float a = 0.f;
  for (int d=0; d<128; d++) a += h2[i*128+d] * w[d*128+c];
  out[gid] = fmaxf(a + b[c], 0.0f);
}

// ---------------- fc2 ----------------
__global__ void fc2_kernel(const float* __restrict__ f1, const float* __restrict__ w,
                           const float* __restrict__ b, float* __restrict__ out) {
  int gid = blockIdx.x*256 + threadIdx.x;   // 16384*40
  int i = gid / 40, c = gid - i*40;
  float a = 0.f;
  for (int d=0; d<128; d++) a += f1[i*128+d] * w[d*40+c];
  out[gid] = a + b[c];
}

extern "C" void kernel_launch(void* const* d_in, const int* in_sizes, int n_in,
                              void* d_out, int out_size, void* d_ws, size_t ws_size,
                              hipStream_t stream) {
  (void)in_sizes; (void)n_in; (void)out_size; (void)ws_size;
  const float* x     = (const float*)d_in[0];
  const float* W1    = (const float*)d_in[1];
  const float* b1    = (const float*)d_in[2];
  const float* W2    = (const float*)d_in[3];
  const float* b2    = (const float*)d_in[4];
  const float* fc1_w = (const float*)d_in[5];
  const float* fc1_b = (const float*)d_in[6];
  const float* fc2_w = (const float*)d_in[7];
  const float* fc2_b = (const float*)d_in[8];
  float* out = (float*)d_out;

  // ---- workspace (31.03 MB total, lifetime-disjoint aliasing; proven R20) ----
  char* ws = (char*)d_ws;
  float4* xp4 = (float4*)(ws + 0);          // 262144
  float*  sqh = (float*) (ws + 262144);     // 65536
  int*    idx = (int*)   (ws + 327680);     // 1310720
  float*  Wd2 = (float*) (ws + 1638400);    // 32768
  float*  h1  = (float*) (ws + 1671168);    // 4194304  -> 5865472
  float*  hTt = (float*) (ws + 5865472);    // 4194304  -> 10059776 (aliases h2-head)
  float*  wsd = (float*) (ws + 10059776);   // 65536    (aliases h2-tail; dead then)
  float*  h2  = (float*) (ws + 5865472);    // 8388608  -> 14254080
  float*  A   = (float*) (ws + 14254080);   // 8388608  -> 22642688
  float*  C1  = A;
  float*  G1  = (float*) (ws + 14254080 + 4194304);
  float*  C2  = A;
  float*  f1  = A;
  float*  G2  = (float*) (ws + 22642688);   // 8388608  -> 31031296
  int*    pi  = (int*)   (ws + 14254080);   // 5.25MB (aliases A; A dead during knn phases)
  float*  pd  = (float*) (ws + 22642688);   // 5.25MB (aliases G2; G2 dead during knn phases)

  pack3_kernel <<<64,   256, 0, stream>>>(x, xp4);
  knn3_wq      <<<1024, 256, 0, stream>>>(xp4, pd, pi);
  knn_merge_kernel<<<64,256, 0, stream>>>(pd, pi, idx);
  cg1_kernel   <<<4096, 256, 0, stream>>>(x, W1, b1, C1, G1);
  maxrelu_kernel<64> <<<4096, 256, 0, stream>>>(C1, G1, idx, h1);
  transpose64_kernel<<<256, 256, 0, stream>>>(h1, hTt);
  sq64_kernel  <<<64,   256, 0, stream>>>(h1, sqh);
  seed64_kernel<<<64,   256, 0, stream>>>(h1, sqh, idx, wsd);
  knn64_wq     <<<1024, 256, 0, stream>>>(h1, hTt, sqh, wsd, pd, pi);
  knn_merge_kernel<<<64,256, 0, stream>>>(pd, pi, idx);
  wd2_kernel   <<<32,   256, 0, stream>>>(W2, Wd2);
  cg2_kernel   <<<8192, 256, 0, stream>>>(h1, W2, Wd2, b2, C2, G2);
  maxrelu_kernel<128><<<8192, 256, 0, stream>>>(C2, G2, idx, h2);
  fc1_kernel   <<<8192, 256, 0, stream>>>(h2, fc1_w, fc1_b, f1);
  fc2_kernel   <<<2560, 256, 0, stream>>>(f1, fc2_w, fc2_b, out);
}